// Round 8
// baseline (524.534 us; speedup 1.0000x reference)
//
#include <hip/hip_runtime.h>

#define HIDDEN 512
#define BLK_ELEMS (64 * 128 * 8)   // elements per (128-row x 512-col) tiled block

typedef __attribute__((ext_vector_type(8))) short short8;
typedef __attribute__((ext_vector_type(4))) float f32x4;

__device__ __forceinline__ unsigned short f2bf(float f) {
    unsigned u = __float_as_uint(f);
    unsigned r = (u + 0x7FFFu + ((u >> 16) & 1u)) >> 16;
    return (unsigned short)r;
}
__device__ __forceinline__ float bf2f(unsigned short h) {
    return __uint_as_float(((unsigned)h) << 16);
}

__device__ __forceinline__ void load_lds16(const unsigned short* g, unsigned short* l) {
    __builtin_amdgcn_global_load_lds(
        (const __attribute__((address_space(1))) unsigned int*)(g),
        (__attribute__((address_space(3))) unsigned int*)(l), 16, 0, 0);
}

__device__ __forceinline__ void acc8(uint4 v, float cf, float* a) {
    a[0] = fmaf(cf, bf2f((unsigned short)(v.x & 0xFFFF)), a[0]);
    a[1] = fmaf(cf, bf2f((unsigned short)(v.x >> 16)),    a[1]);
    a[2] = fmaf(cf, bf2f((unsigned short)(v.y & 0xFFFF)), a[2]);
    a[3] = fmaf(cf, bf2f((unsigned short)(v.y >> 16)),    a[3]);
    a[4] = fmaf(cf, bf2f((unsigned short)(v.z & 0xFFFF)), a[4]);
    a[5] = fmaf(cf, bf2f((unsigned short)(v.z >> 16)),    a[5]);
    a[6] = fmaf(cf, bf2f((unsigned short)(v.w & 0xFFFF)), a[6]);
    a[7] = fmaf(cf, bf2f((unsigned short)(v.w >> 16)),    a[7]);
}

// ---------------- cast fp32 row-major -> tiled bf16 ----------------
// tiled layout: [row/128][kchunk(64)][row%128][8 bf16]

__device__ __forceinline__ void cast_chunk(const float* __restrict__ src,
                                           unsigned short* __restrict__ dst,
                                           int rows, int o) {
    int blk = o >> 13;
    int rem = o & 8191;
    int g = rem >> 7;
    int m = rem & 127;
    int row = blk * 128 + m;
    short8 v;
    if (row < rows) {
        const float* p = src + (size_t)row * HIDDEN + g * 8;
        float4 f0 = *(const float4*)p;
        float4 f1 = *(const float4*)(p + 4);
        v[0] = (short)f2bf(f0.x); v[1] = (short)f2bf(f0.y);
        v[2] = (short)f2bf(f0.z); v[3] = (short)f2bf(f0.w);
        v[4] = (short)f2bf(f1.x); v[5] = (short)f2bf(f1.y);
        v[6] = (short)f2bf(f1.z); v[7] = (short)f2bf(f1.w);
    } else {
        v = (short8)0;
    }
    *(short8*)(dst + (size_t)o * 8) = v;
}

// ---------------- fused: edge-count | cast x ----------------

__global__ __launch_bounds__(256)
void fused_count_castx(const int* __restrict__ dstv, int* __restrict__ cnt, int E, int countB,
                       const float* __restrict__ x, unsigned short* __restrict__ bufA,
                       int rows, int xchunks) {
    int b = blockIdx.x;
    if (b < countB) {
        int e = b * 256 + threadIdx.x;
        if (e < E) atomicAdd(&cnt[dstv[e]], 1);
    } else {
        int o = (b - countB) * 256 + threadIdx.x;
        if (o < xchunks) cast_chunk(x, bufA, rows, o);
    }
}

// ---------------- fused: per-block sums + norm | cast W1/W2/Wc ----------------

__global__ __launch_bounds__(256)
void fused_bsum_castw(const int* __restrict__ cnt, float* __restrict__ norm,
                      int* __restrict__ bsums, int n, int NSB,
                      const float* __restrict__ W1, const float* __restrict__ W2,
                      const float* __restrict__ Wc,
                      unsigned short* __restrict__ W1t, unsigned short* __restrict__ W2t,
                      unsigned short* __restrict__ Wct, int NC) {
    __shared__ int red[256];
    int tid = threadIdx.x;
    if ((int)blockIdx.x < NSB) {
        int i = blockIdx.x * 256 + tid;
        int v = 0;
        if (i < n) {
            v = cnt[i];
            norm[i] = rsqrtf((float)(v + 1));
        }
        red[tid] = v;
        __syncthreads();
        #pragma unroll
        for (int off = 128; off > 0; off >>= 1) {
            if (tid < off) red[tid] += red[tid + off];
            __syncthreads();
        }
        if (tid == 0) bsums[blockIdx.x] = red[0];
    } else {
        int o = ((int)blockIdx.x - NSB) * 256 + tid;
        if (o < 32768) {
            cast_chunk(W1, W1t, HIDDEN, o);
        } else if (o < 65536) {
            cast_chunk(W2, W2t, HIDDEN, o - 32768);
        } else if (o < 73728) {
            cast_chunk(Wc, Wct, NC, o - 65536);
        }
    }
}

// scans nb (<=256) block sums; writes exclusive offsets + total into rowptr[n]
__global__ __launch_bounds__(256)
void bscan_kernel(const int* __restrict__ bsums, int* __restrict__ boffs,
                  int* __restrict__ rowptr_n, int nb) {
    __shared__ int buf[256];
    int tid = threadIdx.x;
    int v = (tid < nb) ? bsums[tid] : 0;
    buf[tid] = v;
    __syncthreads();
    #pragma unroll
    for (int off = 1; off < 256; off <<= 1) {
        int t = (tid >= off) ? buf[tid - off] : 0;
        __syncthreads();
        buf[tid] += t;
        __syncthreads();
    }
    if (tid < nb) boffs[tid] = buf[tid] - v;
    if (tid == 255) rowptr_n[0] = buf[255];
}

__global__ __launch_bounds__(256)
void scan_final_kernel(const int* __restrict__ cnt, const int* __restrict__ boffs,
                       int* __restrict__ rowptr, int* __restrict__ cursor, int n) {
    __shared__ int buf[256];
    int tid = threadIdx.x;
    int i = blockIdx.x * 256 + tid;
    int v = (i < n) ? cnt[i] : 0;
    buf[tid] = v;
    __syncthreads();
    #pragma unroll
    for (int off = 1; off < 256; off <<= 1) {
        int t = (tid >= off) ? buf[tid - off] : 0;
        __syncthreads();
        buf[tid] += t;
        __syncthreads();
    }
    if (i < n) {
        int ex = boffs[blockIdx.x] + buf[tid] - v;
        rowptr[i] = ex;
        cursor[i] = ex;
    }
}

// ---------------- bf16 MFMA GEMM body ----------------
// C[M,N] = A[M,K] @ W[N,K]^T, A/W tiled bf16, K=512.
// MODE 0: C bf16 row-major [M][512].  MODE 1: C fp32 [M][NC] + bias, col<NC guard.

template<int MODE>
__device__ __forceinline__ void gemm_body(const unsigned short* __restrict__ At,
                                          const unsigned short* __restrict__ Bt,
                                          const float* __restrict__ bias,
                                          void* __restrict__ Cout,
                                          int M, int NC, int mb, int nb) {
    __shared__ __align__(16) unsigned short As[8 * 128 * 8];  // 16 KB: [g][m][8]
    __shared__ __align__(16) unsigned short Bs[8 * 128 * 8];

    const int tid = threadIdx.x;
    const int wid = tid >> 6;
    const int lane = tid & 63;
    const int wm = wid & 1, wn = wid >> 1;
    const int lm = lane & 15;
    const int lq = lane >> 4;

    const unsigned short* Ab = At + (size_t)mb * BLK_ELEMS;
    const unsigned short* Bb = Bt + (size_t)nb * BLK_ELEMS;

    f32x4 acc[4][4];
    #pragma unroll
    for (int i = 0; i < 4; ++i)
        #pragma unroll
        for (int j = 0; j < 4; ++j) acc[i][j] = (f32x4)0.f;

    for (int kt = 0; kt < 8; ++kt) {
        __syncthreads();
        const unsigned short* ga = Ab + kt * (8 * 1024);
        const unsigned short* gb = Bb + kt * (8 * 1024);
        #pragma unroll
        for (int i = 0; i < 4; ++i) {
            int off = (tid + i * 256) * 8;
            load_lds16(ga + off, As + off);
            load_lds16(gb + off, Bs + off);
        }
        __syncthreads();
        #pragma unroll
        for (int ks = 0; ks < 2; ++ks) {
            int g = ks * 4 + lq;
            int base = g * 1024 + lm * 8;
            short8 af[4], bfr[4];
            #pragma unroll
            for (int mt = 0; mt < 4; ++mt)
                af[mt] = *(const short8*)&As[base + (wm * 64 + mt * 16) * 8];
            #pragma unroll
            for (int nt = 0; nt < 4; ++nt)
                bfr[nt] = *(const short8*)&Bs[base + (wn * 64 + nt * 16) * 8];
            #pragma unroll
            for (int mt = 0; mt < 4; ++mt)
                #pragma unroll
                for (int nt = 0; nt < 4; ++nt)
                    acc[mt][nt] = __builtin_amdgcn_mfma_f32_16x16x32_bf16(
                        af[mt], bfr[nt], acc[mt][nt], 0, 0, 0);
        }
    }

    #pragma unroll
    for (int mt = 0; mt < 4; ++mt) {
        #pragma unroll
        for (int nt = 0; nt < 4; ++nt) {
            int col = nb * 128 + wn * 64 + nt * 16 + lm;
            f32x4 v = acc[mt][nt];
            #pragma unroll
            for (int r = 0; r < 4; ++r) {
                int row = mb * 128 + wm * 64 + mt * 16 + lq * 4 + r;
                if (row < M) {
                    if (MODE == 0) {
                        ((unsigned short*)Cout)[(size_t)row * HIDDEN + col] = f2bf(v[r]);
                    } else {
                        if (col < NC)
                            ((float*)Cout)[(size_t)row * NC + col] = v[r] + bias[col];
                    }
                }
            }
        }
    }
}

// XCD-grouped swizzle: 4 nb blocks of one mb land on one XCD back-to-back
__device__ __forceinline__ bool swz_decode(int bid, int NB, int& mb, int& nb) {
    int p = bid & 7;
    int s = bid >> 3;
    nb = s & 3;
    mb = (s >> 2) * 8 + p;
    return mb < NB;
}

template<int MODE>
__global__ __launch_bounds__(256)
void gemm_swz(const unsigned short* __restrict__ At, const unsigned short* __restrict__ Bt,
              const float* __restrict__ bias, void* __restrict__ Cout,
              int M, int NC, int NB) {
    int mb, nb;
    if (!swz_decode(blockIdx.x, NB, mb, nb)) return;
    gemm_body<MODE>(At, Bt, bias, Cout, M, NC, mb, nb);
}

template<int MODE>
__global__ __launch_bounds__(256)
void gemm_plain(const unsigned short* __restrict__ At, const unsigned short* __restrict__ Bt,
                const float* __restrict__ bias, void* __restrict__ Cout,
                int M, int NC) {
    gemm_body<MODE>(At, Bt, bias, Cout, M, NC, blockIdx.x, blockIdx.y);
}

// ---------------- fused: CSR fill | gemm layer-1 ----------------

__global__ __launch_bounds__(256)
void fused_fill_gemm1(const int* __restrict__ src, const int* __restrict__ dstv,
                      const float* __restrict__ norm, int* __restrict__ cursor,
                      int2* __restrict__ epair, int E, int fillB,
                      const unsigned short* __restrict__ At, const unsigned short* __restrict__ Bt,
                      void* __restrict__ Cout, int M, int NB) {
    int b = blockIdx.x;
    if (b < fillB) {
        int e = b * 256 + threadIdx.x;
        if (e < E) {
            int s = src[e], d = dstv[e];
            float cf = norm[s] * norm[d];
            int p = atomicAdd(&cursor[d], 1);
            epair[p] = make_int2(s, __float_as_int(cf));
        }
    } else {
        int mb, nb;
        if (swz_decode(b - fillB, NB, mb, nb))
            gemm_body<0>(At, Bt, nullptr, Cout, M, HIDDEN, mb, nb);
    }
}

// ---------------- aggregation: column-pass split, 4 edge-slots per wave ----------------
// gridDim.y = 4 passes; pass p covers cols [128p, 128p+128) — per-pass gather
// working set is 12.75 MB (vs 51 MB), sized for L2/L3 retention.
// Wave = 4 slots x 16 lanes; slot s processes edges beg+s, beg+s+4, ... (256 B row-slice
// per edge per slot => 1 KB per wave-iteration, same instruction efficiency as before).
// Slot partials combined via shfl_xor butterfly; slot 0 writes tiled-bf16 output.

__global__ __launch_bounds__(256)
void aggregate_pass_kernel(const unsigned short* __restrict__ h, const int* __restrict__ rowptr,
                           const int2* __restrict__ epair, const float* __restrict__ norm,
                           const float* __restrict__ bias, unsigned short* __restrict__ out_t,
                           int N) {
    const int wave = threadIdx.x >> 6;
    const int lane = threadIdx.x & 63;
    const int slot = lane >> 4;       // 0..3 edge slot
    const int q    = lane & 15;       // 16B sub-slice within the 128-col slice
    const int node = blockIdx.x * 4 + wave;
    const int pass = blockIdx.y;      // 0..3 column slice
    if (node >= N) return;

    const int col0 = pass * 128 + q * 8;
    const unsigned short* hbase = h + col0;    // + src*HIDDEN

    float a[8] = {0.f, 0.f, 0.f, 0.f, 0.f, 0.f, 0.f, 0.f};
    float nv = norm[node];
    if (slot == 0) {
        uint4 sv = *(const uint4*)(hbase + (size_t)node * HIDDEN);
        acc8(sv, nv * nv, a);
    }

    const int beg = rowptr[node], end = rowptr[node + 1];
    int j = beg + slot;
    for (; j + 4 < end; j += 8) {
        int2 p0 = epair[j];
        int2 p1 = epair[j + 4];
        uint4 v0 = *(const uint4*)(hbase + (size_t)p0.x * HIDDEN);
        uint4 v1 = *(const uint4*)(hbase + (size_t)p1.x * HIDDEN);
        acc8(v0, __int_as_float(p0.y), a);
        acc8(v1, __int_as_float(p1.y), a);
    }
    if (j < end) {
        int2 p0 = epair[j];
        uint4 v0 = *(const uint4*)(hbase + (size_t)p0.x * HIDDEN);
        acc8(v0, __int_as_float(p0.y), a);
    }

    // combine the 4 slots: butterfly over lane bits 4,5
    #pragma unroll
    for (int k = 0; k < 8; ++k) {
        a[k] += __shfl_xor(a[k], 16, 64);
        a[k] += __shfl_xor(a[k], 32, 64);
    }

    if (slot == 0) {
        const float4 b0 = *(const float4*)(bias + col0);
        const float4 b1 = *(const float4*)(bias + col0 + 4);
        a[0] = fmaxf(a[0] + b0.x, 0.f); a[1] = fmaxf(a[1] + b0.y, 0.f);
        a[2] = fmaxf(a[2] + b0.z, 0.f); a[3] = fmaxf(a[3] + b0.w, 0.f);
        a[4] = fmaxf(a[4] + b1.x, 0.f); a[5] = fmaxf(a[5] + b1.y, 0.f);
        a[6] = fmaxf(a[6] + b1.z, 0.f); a[7] = fmaxf(a[7] + b1.w, 0.f);
        // tiled write: chunk g = pass*16 + q of this node's row
        size_t off = (size_t)(node >> 7) * BLK_ELEMS + (size_t)(pass * 16 + q) * 1024
                   + (size_t)(node & 127) * 8;
        uint4 o;
        o.x = (unsigned)f2bf(a[0]) | ((unsigned)f2bf(a[1]) << 16);
        o.y = (unsigned)f2bf(a[2]) | ((unsigned)f2bf(a[3]) << 16);
        o.z = (unsigned)f2bf(a[4]) | ((unsigned)f2bf(a[5]) << 16);
        o.w = (unsigned)f2bf(a[6]) | ((unsigned)f2bf(a[7]) << 16);
        *(uint4*)(out_t + off) = o;
    }
}

// ---------------- launch ----------------

extern "C" void kernel_launch(void* const* d_in, const int* in_sizes, int n_in,
                              void* d_out, int out_size, void* d_ws, size_t ws_size,
                              hipStream_t stream) {
    const float* x  = (const float*)d_in[0];
    const int*   ei = (const int*)d_in[1];
    const float* W1 = (const float*)d_in[2];
    const float* b1 = (const float*)d_in[3];
    const float* W2 = (const float*)d_in[4];
    const float* b2 = (const float*)d_in[5];
    const float* Wc = (const float*)d_in[6];
    const float* bc = (const float*)d_in[7];

    const int N  = in_sizes[0] / HIDDEN;      // 50000
    const int E  = in_sizes[1] / 2;           // 500000
    const int NC = in_sizes[6] / HIDDEN;      // 100
    const int NB = (N + 127) / 128;           // 391
    const int NSB = (N + 255) / 256;          // 196

    const int* src = ei;
    const int* dst = ei + E;

    // ws layout (KB offsets): cnt@0, rowptr@256, cursor@512, normv@768 (ends ~963.3),
    // bsums@968, boffs@990, epair@1024. bsums/boffs must sit after normv's end.
    char* ws = (char*)d_ws;
    int*   cnt    = (int*)(ws);
    int*   rowptr = (int*)(ws + (256 << 10));
    int*   cursor = (int*)(ws + (512 << 10));
    float* normv  = (float*)(ws + (768 << 10));
    int*   bsums  = (int*)(ws + (968 << 10));
    int*   boffs  = (int*)(ws + (990 << 10));
    int2*  epair  = (int2*)(ws + (1ull << 20));                 // E*8 B = 4 MB
    unsigned short* W1t = (unsigned short*)(ws + (6ull << 20));
    unsigned short* W2t = (unsigned short*)(ws + (6ull << 20) + (512 << 10));
    unsigned short* Wct = (unsigned short*)(ws + (7ull << 20));
    unsigned short* bufA = (unsigned short*)(ws + (16ull << 20));
    unsigned short* bufB = (unsigned short*)(ws + (80ull << 20));
    unsigned short* hbuf = (unsigned short*)(ws + (144ull << 20));

    const int countB = (E + 255) / 256;                 // 1954
    const int xchunks = NB * 8192;
    const int castxB = (xchunks + 255) / 256;           // 12512
    const int gemmB = 8 * 4 * ((NB + 7) / 8);           // 1568

    hipMemsetAsync(cnt, 0, N * sizeof(int), stream);
    // [edge count | cast x]
    fused_count_castx<<<countB + castxB, 256, 0, stream>>>(dst, cnt, E, countB,
                                                           x, bufA, N, xchunks);
    // [block sums + norm | cast W1/W2/Wc]
    fused_bsum_castw<<<NSB + 288, 256, 0, stream>>>(cnt, normv, bsums, N, NSB,
                                                    W1, W2, Wc, W1t, W2t, Wct, NC);
    bscan_kernel<<<1, 256, 0, stream>>>(bsums, boffs, rowptr + N, NSB);
    scan_final_kernel<<<NSB, 256, 0, stream>>>(cnt, boffs, rowptr, cursor, N);
    // [CSR fill | gemm layer-1]
    fused_fill_gemm1<<<countB + gemmB, 256, 0, stream>>>(src, dst, normv, cursor, epair,
                                                         E, countB,
                                                         bufA, W1t, hbuf, N, NB);
    dim3 gagg((N + 3) / 4, 4);
    aggregate_pass_kernel<<<gagg, 256, 0, stream>>>(hbuf, rowptr, epair, normv, b1, bufB, N);
    gemm_swz<0><<<gemmB, 256, 0, stream>>>(bufB, W2t, nullptr, hbuf, N, HIDDEN, NB);
    aggregate_pass_kernel<<<gagg, 256, 0, stream>>>(hbuf, rowptr, epair, normv, b2, bufA, N);
    gemm_plain<1><<<dim3(NB, 1), 256, 0, stream>>>(bufA, Wct, bc, d_out, N, NC);
}

// Round 9
// 501.054 us; speedup vs baseline: 1.0469x; 1.0469x over previous
//
#include <hip/hip_runtime.h>

#define HIDDEN 512
#define BLK_ELEMS (64 * 128 * 8)   // elements per (128-row x 512-col) tiled block

typedef __attribute__((ext_vector_type(8))) short short8;
typedef __attribute__((ext_vector_type(4))) float f32x4;

__device__ __forceinline__ unsigned short f2bf(float f) {
    unsigned u = __float_as_uint(f);
    unsigned r = (u + 0x7FFFu + ((u >> 16) & 1u)) >> 16;
    return (unsigned short)r;
}
__device__ __forceinline__ float bf2f(unsigned short h) {
    return __uint_as_float(((unsigned)h) << 16);
}

__device__ __forceinline__ void load_lds16(const unsigned short* g, unsigned short* l) {
    __builtin_amdgcn_global_load_lds(
        (const __attribute__((address_space(1))) unsigned int*)(g),
        (__attribute__((address_space(3))) unsigned int*)(l), 16, 0, 0);
}

__device__ __forceinline__ void acc8(uint4 v, float cf, float* a) {
    a[0] = fmaf(cf, bf2f((unsigned short)(v.x & 0xFFFF)), a[0]);
    a[1] = fmaf(cf, bf2f((unsigned short)(v.x >> 16)),    a[1]);
    a[2] = fmaf(cf, bf2f((unsigned short)(v.y & 0xFFFF)), a[2]);
    a[3] = fmaf(cf, bf2f((unsigned short)(v.y >> 16)),    a[3]);
    a[4] = fmaf(cf, bf2f((unsigned short)(v.z & 0xFFFF)), a[4]);
    a[5] = fmaf(cf, bf2f((unsigned short)(v.z >> 16)),    a[5]);
    a[6] = fmaf(cf, bf2f((unsigned short)(v.w & 0xFFFF)), a[6]);
    a[7] = fmaf(cf, bf2f((unsigned short)(v.w >> 16)),    a[7]);
}

// ---------------- cast fp32 row-major -> tiled bf16 ----------------
// tiled layout: [row/128][kchunk(64)][row%128][8 bf16]

__device__ __forceinline__ void cast_chunk(const float* __restrict__ src,
                                           unsigned short* __restrict__ dst,
                                           int rows, int o) {
    int blk = o >> 13;
    int rem = o & 8191;
    int g = rem >> 7;
    int m = rem & 127;
    int row = blk * 128 + m;
    short8 v;
    if (row < rows) {
        const float* p = src + (size_t)row * HIDDEN + g * 8;
        float4 f0 = *(const float4*)p;
        float4 f1 = *(const float4*)(p + 4);
        v[0] = (short)f2bf(f0.x); v[1] = (short)f2bf(f0.y);
        v[2] = (short)f2bf(f0.z); v[3] = (short)f2bf(f0.w);
        v[4] = (short)f2bf(f1.x); v[5] = (short)f2bf(f1.y);
        v[6] = (short)f2bf(f1.z); v[7] = (short)f2bf(f1.w);
    } else {
        v = (short8)0;
    }
    *(short8*)(dst + (size_t)o * 8) = v;
}

// ---------------- fused: edge-count | cast x ----------------

__global__ __launch_bounds__(256)
void fused_count_castx(const int* __restrict__ dstv, int* __restrict__ cnt, int E, int countB,
                       const float* __restrict__ x, unsigned short* __restrict__ bufA,
                       int rows, int xchunks) {
    int b = blockIdx.x;
    if (b < countB) {
        int e = b * 256 + threadIdx.x;
        if (e < E) atomicAdd(&cnt[dstv[e]], 1);
    } else {
        int o = (b - countB) * 256 + threadIdx.x;
        if (o < xchunks) cast_chunk(x, bufA, rows, o);
    }
}

// ---------------- fused: per-block sums + norm | cast W1/W2/Wc ----------------

__global__ __launch_bounds__(256)
void fused_bsum_castw(const int* __restrict__ cnt, float* __restrict__ norm,
                      int* __restrict__ bsums, int n, int NSB,
                      const float* __restrict__ W1, const float* __restrict__ W2,
                      const float* __restrict__ Wc,
                      unsigned short* __restrict__ W1t, unsigned short* __restrict__ W2t,
                      unsigned short* __restrict__ Wct, int NC) {
    __shared__ int red[256];
    int tid = threadIdx.x;
    if ((int)blockIdx.x < NSB) {
        int i = blockIdx.x * 256 + tid;
        int v = 0;
        if (i < n) {
            v = cnt[i];
            norm[i] = rsqrtf((float)(v + 1));
        }
        red[tid] = v;
        __syncthreads();
        #pragma unroll
        for (int off = 128; off > 0; off >>= 1) {
            if (tid < off) red[tid] += red[tid + off];
            __syncthreads();
        }
        if (tid == 0) bsums[blockIdx.x] = red[0];
    } else {
        int o = ((int)blockIdx.x - NSB) * 256 + tid;
        if (o < 32768) {
            cast_chunk(W1, W1t, HIDDEN, o);
        } else if (o < 65536) {
            cast_chunk(W2, W2t, HIDDEN, o - 32768);
        } else if (o < 73728) {
            cast_chunk(Wc, Wct, NC, o - 65536);
        }
    }
}

// scans nb (<=256) block sums; writes exclusive offsets + total into rowptr[n]
__global__ __launch_bounds__(256)
void bscan_kernel(const int* __restrict__ bsums, int* __restrict__ boffs,
                  int* __restrict__ rowptr_n, int nb) {
    __shared__ int buf[256];
    int tid = threadIdx.x;
    int v = (tid < nb) ? bsums[tid] : 0;
    buf[tid] = v;
    __syncthreads();
    #pragma unroll
    for (int off = 1; off < 256; off <<= 1) {
        int t = (tid >= off) ? buf[tid - off] : 0;
        __syncthreads();
        buf[tid] += t;
        __syncthreads();
    }
    if (tid < nb) boffs[tid] = buf[tid] - v;
    if (tid == 255) rowptr_n[0] = buf[255];
}

__global__ __launch_bounds__(256)
void scan_final_kernel(const int* __restrict__ cnt, const int* __restrict__ boffs,
                       int* __restrict__ rowptr, int* __restrict__ cursor, int n) {
    __shared__ int buf[256];
    int tid = threadIdx.x;
    int i = blockIdx.x * 256 + tid;
    int v = (i < n) ? cnt[i] : 0;
    buf[tid] = v;
    __syncthreads();
    #pragma unroll
    for (int off = 1; off < 256; off <<= 1) {
        int t = (tid >= off) ? buf[tid - off] : 0;
        __syncthreads();
        buf[tid] += t;
        __syncthreads();
    }
    if (i < n) {
        int ex = boffs[blockIdx.x] + buf[tid] - v;
        rowptr[i] = ex;
        cursor[i] = ex;
    }
}

// ---------------- bf16 MFMA GEMM body ----------------
// C[M,N] = A[M,K] @ W[N,K]^T, A/W tiled bf16, K=512.
// MODE 0: C bf16 row-major [M][512].  MODE 1: C fp32 [M][NC] + bias, col<NC guard.

template<int MODE>
__device__ __forceinline__ void gemm_body(const unsigned short* __restrict__ At,
                                          const unsigned short* __restrict__ Bt,
                                          const float* __restrict__ bias,
                                          void* __restrict__ Cout,
                                          int M, int NC, int mb, int nb) {
    __shared__ __align__(16) unsigned short As[8 * 128 * 8];  // 16 KB: [g][m][8]
    __shared__ __align__(16) unsigned short Bs[8 * 128 * 8];

    const int tid = threadIdx.x;
    const int wid = tid >> 6;
    const int lane = tid & 63;
    const int wm = wid & 1, wn = wid >> 1;
    const int lm = lane & 15;
    const int lq = lane >> 4;

    const unsigned short* Ab = At + (size_t)mb * BLK_ELEMS;
    const unsigned short* Bb = Bt + (size_t)nb * BLK_ELEMS;

    f32x4 acc[4][4];
    #pragma unroll
    for (int i = 0; i < 4; ++i)
        #pragma unroll
        for (int j = 0; j < 4; ++j) acc[i][j] = (f32x4)0.f;

    for (int kt = 0; kt < 8; ++kt) {
        __syncthreads();
        const unsigned short* ga = Ab + kt * (8 * 1024);
        const unsigned short* gb = Bb + kt * (8 * 1024);
        #pragma unroll
        for (int i = 0; i < 4; ++i) {
            int off = (tid + i * 256) * 8;
            load_lds16(ga + off, As + off);
            load_lds16(gb + off, Bs + off);
        }
        __syncthreads();
        #pragma unroll
        for (int ks = 0; ks < 2; ++ks) {
            int g = ks * 4 + lq;
            int base = g * 1024 + lm * 8;
            short8 af[4], bfr[4];
            #pragma unroll
            for (int mt = 0; mt < 4; ++mt)
                af[mt] = *(const short8*)&As[base + (wm * 64 + mt * 16) * 8];
            #pragma unroll
            for (int nt = 0; nt < 4; ++nt)
                bfr[nt] = *(const short8*)&Bs[base + (wn * 64 + nt * 16) * 8];
            #pragma unroll
            for (int mt = 0; mt < 4; ++mt)
                #pragma unroll
                for (int nt = 0; nt < 4; ++nt)
                    acc[mt][nt] = __builtin_amdgcn_mfma_f32_16x16x32_bf16(
                        af[mt], bfr[nt], acc[mt][nt], 0, 0, 0);
        }
    }

    #pragma unroll
    for (int mt = 0; mt < 4; ++mt) {
        #pragma unroll
        for (int nt = 0; nt < 4; ++nt) {
            int col = nb * 128 + wn * 64 + nt * 16 + lm;
            f32x4 v = acc[mt][nt];
            #pragma unroll
            for (int r = 0; r < 4; ++r) {
                int row = mb * 128 + wm * 64 + mt * 16 + lq * 4 + r;
                if (row < M) {
                    if (MODE == 0) {
                        ((unsigned short*)Cout)[(size_t)row * HIDDEN + col] = f2bf(v[r]);
                    } else {
                        if (col < NC)
                            ((float*)Cout)[(size_t)row * NC + col] = v[r] + bias[col];
                    }
                }
            }
        }
    }
}

// XCD-grouped swizzle: 4 nb blocks of one mb land on one XCD back-to-back
__device__ __forceinline__ bool swz_decode(int bid, int NB, int& mb, int& nb) {
    int p = bid & 7;
    int s = bid >> 3;
    nb = s & 3;
    mb = (s >> 2) * 8 + p;
    return mb < NB;
}

template<int MODE>
__global__ __launch_bounds__(256)
void gemm_swz(const unsigned short* __restrict__ At, const unsigned short* __restrict__ Bt,
              const float* __restrict__ bias, void* __restrict__ Cout,
              int M, int NC, int NB) {
    int mb, nb;
    if (!swz_decode(blockIdx.x, NB, mb, nb)) return;
    gemm_body<MODE>(At, Bt, bias, Cout, M, NC, mb, nb);
}

template<int MODE>
__global__ __launch_bounds__(256)
void gemm_plain(const unsigned short* __restrict__ At, const unsigned short* __restrict__ Bt,
                const float* __restrict__ bias, void* __restrict__ Cout,
                int M, int NC) {
    gemm_body<MODE>(At, Bt, bias, Cout, M, NC, blockIdx.x, blockIdx.y);
}

// ---------------- fused: CSR fill | gemm layer-1 ----------------

__global__ __launch_bounds__(256)
void fused_fill_gemm1(const int* __restrict__ src, const int* __restrict__ dstv,
                      const float* __restrict__ norm, int* __restrict__ cursor,
                      int2* __restrict__ epair, int E, int fillB,
                      const unsigned short* __restrict__ At, const unsigned short* __restrict__ Bt,
                      void* __restrict__ Cout, int M, int NB) {
    int b = blockIdx.x;
    if (b < fillB) {
        int e = b * 256 + threadIdx.x;
        if (e < E) {
            int s = src[e], d = dstv[e];
            float cf = norm[s] * norm[d];
            int p = atomicAdd(&cursor[d], 1);
            epair[p] = make_int2(s, __float_as_int(cf));
        }
    } else {
        int mb, nb;
        if (swz_decode(b - fillB, NB, mb, nb))
            gemm_body<0>(At, Bt, nullptr, Cout, M, HIDDEN, mb, nb);
    }
}

// ---------------- aggregation: wave-per-node, 16 waves/block for full-line writes ----
// out[i] = relu( sum_e coef[e]*h[src[e]] + norm[i]^2*h[i] + b ), written tiled-bf16.
// 1024-thread blocks cover 16 ALIGNED consecutive nodes so the 16B-per-lane tiled
// writes (2KB lane stride, 16B node stride) assemble into full 128B lines within
// one block -> kills the 1.7x write amplification seen in R5-R7 (WRITE 87MB vs 51MB).

__global__ __launch_bounds__(1024)
void aggregate_kernel(const unsigned short* __restrict__ h, const int* __restrict__ rowptr,
                      const int2* __restrict__ epair, const float* __restrict__ norm,
                      const float* __restrict__ bias, unsigned short* __restrict__ out_t,
                      int N) {
    const int wave = threadIdx.x >> 6;
    const int lane = threadIdx.x & 63;
    const int node = blockIdx.x * 16 + wave;
    if (node >= N) return;
    const uint4* h4 = (const uint4*)h;   // 64 chunks of 16B per row
    const int c = lane;

    float a[8];
    {
        uint4 sv = h4[(size_t)node * 64 + c];
        float nv = norm[node];
        float invd = nv * nv;
        a[0] = a[1] = a[2] = a[3] = a[4] = a[5] = a[6] = a[7] = 0.f;
        acc8(sv, invd, a);
    }

    int beg = rowptr[node], end = rowptr[node + 1];
    int j = beg;
    for (; j + 4 <= end; j += 4) {
        int2 p0 = epair[j + 0];
        int2 p1 = epair[j + 1];
        int2 p2 = epair[j + 2];
        int2 p3 = epair[j + 3];
        uint4 v0 = h4[(size_t)p0.x * 64 + c];
        uint4 v1 = h4[(size_t)p1.x * 64 + c];
        uint4 v2 = h4[(size_t)p2.x * 64 + c];
        uint4 v3 = h4[(size_t)p3.x * 64 + c];
        acc8(v0, __int_as_float(p0.y), a);
        acc8(v1, __int_as_float(p1.y), a);
        acc8(v2, __int_as_float(p2.y), a);
        acc8(v3, __int_as_float(p3.y), a);
    }
    for (; j < end; ++j) {
        int2 p = epair[j];
        uint4 v = h4[(size_t)p.x * 64 + c];
        acc8(v, __int_as_float(p.y), a);
    }

    const float4 b0 = *(const float4*)(bias + c * 8);
    const float4 b1 = *(const float4*)(bias + c * 8 + 4);
    a[0] = fmaxf(a[0] + b0.x, 0.f); a[1] = fmaxf(a[1] + b0.y, 0.f);
    a[2] = fmaxf(a[2] + b0.z, 0.f); a[3] = fmaxf(a[3] + b0.w, 0.f);
    a[4] = fmaxf(a[4] + b1.x, 0.f); a[5] = fmaxf(a[5] + b1.y, 0.f);
    a[6] = fmaxf(a[6] + b1.z, 0.f); a[7] = fmaxf(a[7] + b1.w, 0.f);

    // tiled write: lane owns chunk g=c of this node's row
    size_t off = (size_t)(node >> 7) * BLK_ELEMS + (size_t)c * 1024 + (node & 127) * 8;
    uint4 o;
    o.x = (unsigned)f2bf(a[0]) | ((unsigned)f2bf(a[1]) << 16);
    o.y = (unsigned)f2bf(a[2]) | ((unsigned)f2bf(a[3]) << 16);
    o.z = (unsigned)f2bf(a[4]) | ((unsigned)f2bf(a[5]) << 16);
    o.w = (unsigned)f2bf(a[6]) | ((unsigned)f2bf(a[7]) << 16);
    *(uint4*)(out_t + off) = o;
}

// ---------------- launch ----------------

extern "C" void kernel_launch(void* const* d_in, const int* in_sizes, int n_in,
                              void* d_out, int out_size, void* d_ws, size_t ws_size,
                              hipStream_t stream) {
    const float* x  = (const float*)d_in[0];
    const int*   ei = (const int*)d_in[1];
    const float* W1 = (const float*)d_in[2];
    const float* b1 = (const float*)d_in[3];
    const float* W2 = (const float*)d_in[4];
    const float* b2 = (const float*)d_in[5];
    const float* Wc = (const float*)d_in[6];
    const float* bc = (const float*)d_in[7];

    const int N  = in_sizes[0] / HIDDEN;      // 50000
    const int E  = in_sizes[1] / 2;           // 500000
    const int NC = in_sizes[6] / HIDDEN;      // 100
    const int NB = (N + 127) / 128;           // 391
    const int NSB = (N + 255) / 256;          // 196

    const int* src = ei;
    const int* dst = ei + E;

    // ws layout (KB offsets): cnt@0, rowptr@256, cursor@512, normv@768 (ends ~963.3),
    // bsums@968, boffs@990, epair@1024. bsums/boffs must sit after normv's end.
    char* ws = (char*)d_ws;
    int*   cnt    = (int*)(ws);
    int*   rowptr = (int*)(ws + (256 << 10));
    int*   cursor = (int*)(ws + (512 << 10));
    float* normv  = (float*)(ws + (768 << 10));
    int*   bsums  = (int*)(ws + (968 << 10));
    int*   boffs  = (int*)(ws + (990 << 10));
    int2*  epair  = (int2*)(ws + (1ull << 20));                 // E*8 B = 4 MB
    unsigned short* W1t = (unsigned short*)(ws + (6ull << 20));
    unsigned short* W2t = (unsigned short*)(ws + (6ull << 20) + (512 << 10));
    unsigned short* Wct = (unsigned short*)(ws + (7ull << 20));
    unsigned short* bufA = (unsigned short*)(ws + (16ull << 20));
    unsigned short* bufB = (unsigned short*)(ws + (80ull << 20));
    unsigned short* hbuf = (unsigned short*)(ws + (144ull << 20));

    const int countB = (E + 255) / 256;                 // 1954
    const int xchunks = NB * 8192;
    const int castxB = (xchunks + 255) / 256;           // 12512
    const int gemmB = 8 * 4 * ((NB + 7) / 8);           // 1568

    hipMemsetAsync(cnt, 0, N * sizeof(int), stream);
    // [edge count | cast x]
    fused_count_castx<<<countB + castxB, 256, 0, stream>>>(dst, cnt, E, countB,
                                                           x, bufA, N, xchunks);
    // [block sums + norm | cast W1/W2/Wc]
    fused_bsum_castw<<<NSB + 288, 256, 0, stream>>>(cnt, normv, bsums, N, NSB,
                                                    W1, W2, Wc, W1t, W2t, Wct, NC);
    bscan_kernel<<<1, 256, 0, stream>>>(bsums, boffs, rowptr + N, NSB);
    scan_final_kernel<<<NSB, 256, 0, stream>>>(cnt, boffs, rowptr, cursor, N);
    // [CSR fill | gemm layer-1]
    fused_fill_gemm1<<<countB + gemmB, 256, 0, stream>>>(src, dst, normv, cursor, epair,
                                                         E, countB,
                                                         bufA, W1t, hbuf, N, NB);
    const int aggB = (N + 15) / 16;
    aggregate_kernel<<<aggB, 1024, 0, stream>>>(hbuf, rowptr, epair, normv, b1, bufB, N);
    gemm_swz<0><<<gemmB, 256, 0, stream>>>(bufB, W2t, nullptr, hbuf, N, HIDDEN, NB);
    aggregate_kernel<<<aggB, 1024, 0, stream>>>(hbuf, rowptr, epair, normv, b2, bufA, N);
    gemm_plain<1><<<dim3(NB, 1), 256, 0, stream>>>(bufA, Wct, bc, d_out, N, NC);
}